// Round 4
// baseline (2784.758 us; speedup 1.0000x reference)
//
#include <hip/hip_runtime.h>
#include <math.h>

#define NIMG 128
#define HW   256
#define NPX  (HW*HW)

__device__ __forceinline__ int refl_idx(int t) {
  return t < 0 ? -t : (t > 255 ? 510 - t : t);
}

__device__ __forceinline__ unsigned int bf16_rtn(float f) {
  unsigned int u = __float_as_uint(f);
  return (u + 0x7fffu + ((u >> 16) & 1u)) >> 16;
}
__device__ __forceinline__ unsigned int packxy(float x, float y) {
  return bf16_rtn(x) | (bf16_rtn(y) << 16);
}

// ---------------- Kernel A: per-image mean / inv_std (ddof=1) ----------------
__global__ __launch_bounds__(256)
void stats_kernel(const float* __restrict__ pred, const float* __restrict__ targ,
                  float* __restrict__ stats)
{
  const int b = blockIdx.x;        // 0..255
  const int which = b >> 7;        // 0 pred, 1 targ
  const int img = b & 127;
  const float4* src = (const float4*)((which ? targ : pred) + (size_t)img * NPX);
  const int t = threadIdx.x;
  double s = 0.0, s2 = 0.0;
  for (int i = t; i < NPX/4; i += 256) {
    float4 v = src[i];
    s  += (double)v.x + (double)v.y + (double)v.z + (double)v.w;
    s2 += (double)v.x*v.x + (double)v.y*v.y + (double)v.z*v.z + (double)v.w*v.w;
  }
  __shared__ double rs[256], rs2[256];
  rs[t] = s; rs2[t] = s2;
  __syncthreads();
  for (int off = 128; off > 0; off >>= 1) {
    if (t < off) { rs[t] += rs[t+off]; rs2[t] += rs2[t+off]; }
    __syncthreads();
  }
  if (t == 0) {
    const double n = (double)NPX;
    double mean = rs[0] / n;
    double var = (rs2[0] - n*mean*mean) / (n - 1.0);
    stats[(which*NIMG + img)*2 + 0] = (float)mean;
    stats[(which*NIMG + img)*2 + 1] = (float)(1.0 / sqrt(var));
  }
}

// ---------------- Merged SSIM kernel ----------------
// grid: 5 ks * 128 imgs * 8 octs = 5120 blocks, 256 threads.
// Each block: one (ks, image, 32-row band), 4 strips of 8 rows, loops 5 sigmas.
// LDS 32704 B -> up to 5 blocks/CU (20 waves, 62.5% occupancy).

struct SM {
  unsigned int xy[20][256]; // packed bf16: x | y<<16 (standardized, reflect rows)
  float vf[5][2][272];      // vertical-blur fields, 2 rows, cols -8..263 (+8 offset)
  float gw[5][16];          // gaussian weights per sigma
  float red[256];
};

template<int KS>
__device__ __forceinline__ void ssim_body(const float* __restrict__ pred,
                                          const float* __restrict__ targ,
                                          const float* __restrict__ stats,
                                          float* __restrict__ partial,
                                          int sub, int ksi, SM& sm)
{
  constexpr int PAD = (KS - 1) / 2;
  constexpr float C1f = (float)(0.01 * 0.01);
  constexpr float C2f = (float)(0.03 * 0.03);

  const int img = sub >> 3;
  const int oct = sub & 7;
  const int t = threadIdx.x;

  // gaussian weights in double to match numpy
  if (t < 5) {
    const double sigs[5] = {0.8, 1.2, 1.5, 1.8, 2.0};
    double sig = sigs[t];
    double tmp[KS]; double sum = 0.0;
    #pragma unroll
    for (int a = 0; a < KS; ++a) {
      double d = (double)(a - PAD) / sig;
      double e = exp(-0.5 * d * d);
      tmp[a] = e; sum += e;
    }
    #pragma unroll
    for (int a = 0; a < KS; ++a) sm.gw[t][a] = (float)(tmp[a] / sum);
  }

  const float mx = stats[(0*NIMG + img)*2 + 0];
  const float ix = stats[(0*NIMG + img)*2 + 1];
  const float my = stats[(1*NIMG + img)*2 + 0];
  const float iy = stats[(1*NIMG + img)*2 + 1];

  const float4* p4 = (const float4*)(pred + (size_t)img * NPX);
  const float4* t4 = (const float4*)(targ + (size_t)img * NPX);

  float acc = 0.f;

  for (int st = 0; st < 4; ++st) {
    const int r0 = oct*32 + st*8;          // output rows r0 .. r0+7
    __syncthreads();                       // xy reuse + gw visibility
    // stage rows r0-6 .. r0+13 (20 rows, reflect), standardized, bf16-packed
    for (int i = t; i < 20*64; i += 256) {
      const int row = i >> 6, c4 = i & 63;
      const int gr = refl_idx(r0 - 6 + row);
      float4 a = p4[gr*64 + c4];
      float4 b = t4[gr*64 + c4];
      uint4 o;
      o.x = packxy((a.x - mx)*ix, (b.x - my)*iy);
      o.y = packxy((a.y - mx)*ix, (b.y - my)*iy);
      o.z = packxy((a.z - mx)*ix, (b.z - my)*iy);
      o.w = packxy((a.w - mx)*ix, (b.w - my)*iy);
      *(uint4*)&sm.xy[row][c4*4] = o;
    }
    __syncthreads();

    for (int si = 0; si < 5; ++si) {
      float g[KS];
      #pragma unroll
      for (int a = 0; a < KS; ++a) g[a] = sm.gw[si][a];

      for (int ch = 0; ch < 4; ++ch) {
        // ---- vertical pass: thread = logical col, 2 output rows ----
        for (int cc = t - 8; cc < 264; cc += 256) {
          const int rc = cc < 0 ? -cc : (cc > 255 ? 510 - cc : cc);
          float amx[2] = {0,0}, amy[2] = {0,0};
          float axx[2] = {0,0}, ayy[2] = {0,0}, axy[2] = {0,0};
          const int base = ch*2 + 6 - PAD;   // xy row index of (rr=0, tap a=0)
          #pragma unroll
          for (int i2 = 0; i2 < KS + 1; ++i2) {
            const unsigned int u = sm.xy[base + i2][rc];
            const float xv = __uint_as_float(u << 16);
            const float yv = __uint_as_float(u & 0xffff0000u);
            const float xx = xv*xv, yy = yv*yv, xyv = xv*yv;
            #pragma unroll
            for (int rr = 0; rr < 2; ++rr) {
              const int a = i2 - rr;
              if (a >= 0 && a < KS) {
                amx[rr] += g[a]*xv; amy[rr] += g[a]*yv;
                axx[rr] += g[a]*xx; ayy[rr] += g[a]*yy; axy[rr] += g[a]*xyv;
              }
            }
          }
          #pragma unroll
          for (int rr = 0; rr < 2; ++rr) {
            sm.vf[0][rr][cc+8] = amx[rr]; sm.vf[1][rr][cc+8] = amy[rr];
            sm.vf[2][rr][cc+8] = axx[rr]; sm.vf[3][rr][cc+8] = ayy[rr];
            sm.vf[4][rr][cc+8] = axy[rr];
          }
        }
        __syncthreads();

        // ---- horizontal pass + smap: thread = (row rr, 2 consecutive cols) ----
        {
          const int rr = t >> 7;
          const int c0 = (t & 127) * 2;
          const int r  = r0 + ch*2 + rr;
          float h[5][2];
          #pragma unroll
          for (int f = 0; f < 5; ++f) {
            float wv[20];
            #pragma unroll
            for (int j = 0; j < 10; ++j) {
              if (j >= (8 - PAD)/2 && j <= (9 + PAD)/2) {
                const float2 v = *(const float2*)&sm.vf[f][rr][c0 + 2*j];
                wv[2*j+0] = v.x; wv[2*j+1] = v.y;
              }
            }
            #pragma unroll
            for (int p = 0; p < 2; ++p) {
              float s = 0.f;
              #pragma unroll
              for (int b = 0; b < KS; ++b)
                s += g[b] * wv[8 + p - PAD + b];
              h[f][p] = s;
            }
          }
          const bool rok = (r >= PAD) && (r < HW - PAD);
          #pragma unroll
          for (int p = 0; p < 2; ++p) {
            const int c = c0 + p;
            if (rok && c >= PAD && c < HW - PAD) {
              const float hx = h[0][p], hy = h[1][p];
              const float hxx = h[2][p], hyy = h[3][p], hxy = h[4][p];
              const float sx = hxx - hx*hx, sy = hyy - hy*hy, sxy = hxy - hx*hy;
              const float num = (2.f*hx*hy + C1f) * (2.f*sxy + C2f);
              const float den = (hx*hx + hy*hy + C1f) * (sx + sy + C2f);
              acc += num / den;
            }
          }
        }
        __syncthreads();
      } // ch
    } // si
  } // st

  sm.red[t] = acc;
  __syncthreads();
  for (int off = 128; off > 0; off >>= 1) {
    if (t < off) sm.red[t] += sm.red[t+off];
    __syncthreads();
  }
  if (t == 0) {
    constexpr float npix = (float)((HW - 2*PAD) * (HW - 2*PAD));
    partial[ksi*1024 + sub] = sm.red[0] / (npix * 25.f * 128.f);
  }
}

__global__ __launch_bounds__(256, 5)
void ssim_merged(const float* __restrict__ pred, const float* __restrict__ targ,
                 const float* __restrict__ stats, float* __restrict__ partial)
{
  __shared__ SM sm;
  const int bid = blockIdx.x;
  const int ksi = bid % 5;     // block-uniform
  const int sub = bid / 5;
  switch (ksi) {
    case 0: ssim_body<13>(pred, targ, stats, partial, sub, 0, sm); break;
    case 1: ssim_body<11>(pred, targ, stats, partial, sub, 1, sm); break;
    case 2: ssim_body<9> (pred, targ, stats, partial, sub, 2, sm); break;
    case 3: ssim_body<7> (pred, targ, stats, partial, sub, 3, sm); break;
    case 4: ssim_body<5> (pred, targ, stats, partial, sub, 4, sm); break;
  }
}

// ---------------- Kernel C: final deterministic reduction ----------------
__global__ __launch_bounds__(256)
void reduce_kernel(const float* __restrict__ partial, float* __restrict__ out)
{
  const int t = threadIdx.x;
  double s = 0.0;
  for (int i = t; i < 5*1024; i += 256) s += (double)partial[i];
  __shared__ double red[256];
  red[t] = s;
  __syncthreads();
  for (int off = 128; off > 0; off >>= 1) {
    if (t < off) red[t] += red[t+off];
    __syncthreads();
  }
  if (t == 0) out[0] = (float)(0.5 - 0.5 * red[0]);
}

extern "C" void kernel_launch(void* const* d_in, const int* in_sizes, int n_in,
                              void* d_out, int out_size, void* d_ws, size_t ws_size,
                              hipStream_t stream) {
  const float* pred = (const float*)d_in[0];
  const float* targ = (const float*)d_in[1];
  float* out = (float*)d_out;
  float* ws = (float*)d_ws;
  float* stats   = ws;          // 512 floats
  float* partial = ws + 512;    // 5*1024 floats

  stats_kernel<<<256, 256, 0, stream>>>(pred, targ, stats);
  ssim_merged<<<5120, 256, 0, stream>>>(pred, targ, stats, partial);
  reduce_kernel<<<1, 256, 0, stream>>>(partial, out);
}

// Round 6
// 1409.439 us; speedup vs baseline: 1.9758x; 1.9758x over previous
//
#include <hip/hip_runtime.h>
#include <math.h>

#define NIMG 128
#define HW   256
#define NPX  (HW*HW)

__device__ __forceinline__ int refl_idx(int t) {
  return t < 0 ? -t : (t > 255 ? 510 - t : t);
}

__device__ __forceinline__ unsigned int bf16_rtn(float f) {
  unsigned int u = __float_as_uint(f);
  return (u + 0x7fffu + ((u >> 16) & 1u)) >> 16;
}
__device__ __forceinline__ unsigned int packxy(float x, float y) {
  return bf16_rtn(x) | (bf16_rtn(y) << 16);
}

// ---------------- Kernel A: per-image mean / inv_std (ddof=1) ----------------
__global__ __launch_bounds__(256)
void stats_kernel(const float* __restrict__ pred, const float* __restrict__ targ,
                  float* __restrict__ stats)
{
  const int b = blockIdx.x;        // 0..255
  const int which = b >> 7;        // 0 pred, 1 targ
  const int img = b & 127;
  const float4* src = (const float4*)((which ? targ : pred) + (size_t)img * NPX);
  const int t = threadIdx.x;
  double s = 0.0, s2 = 0.0;
  for (int i = t; i < NPX/4; i += 256) {
    float4 v = src[i];
    s  += (double)v.x + (double)v.y + (double)v.z + (double)v.w;
    s2 += (double)v.x*v.x + (double)v.y*v.y + (double)v.z*v.z + (double)v.w*v.w;
  }
  __shared__ double rs[256], rs2[256];
  rs[t] = s; rs2[t] = s2;
  __syncthreads();
  for (int off = 128; off > 0; off >>= 1) {
    if (t < off) { rs[t] += rs[t+off]; rs2[t] += rs2[t+off]; }
    __syncthreads();
  }
  if (t == 0) {
    const double n = (double)NPX;
    double mean = rs[0] / n;
    double var = (rs2[0] - n*mean*mean) / (n - 1.0);
    stats[(which*NIMG + img)*2 + 0] = (float)mean;
    stats[(which*NIMG + img)*2 + 1] = (float)(1.0 / sqrt(var));
  }
}

// ---------------- Merged SSIM kernel ----------------
// grid: 5 ks * 128 imgs * 8 bands = 5120 blocks, 256 threads.
// Each block: one (ks, image, 32-row band), 2 strips of 16 rows, loops 5 sigmas,
// 4-row vf chunks (round-3 proven geometry).
// LDS 51776 B -> 3 blocks/CU (12 waves, 37.5% occupancy).

struct SM {
  unsigned int xy[28][256]; // packed bf16: x | y<<16 (standardized, reflect rows)
  float vf[5][4][272];      // vertical-blur fields, 4 rows, cols -8..263 (+8 offset)
  float gw[5][16];          // gaussian weights per sigma
  float red[256];
};

template<int KS>
__device__ __forceinline__ void ssim_body(const float* __restrict__ pred,
                                          const float* __restrict__ targ,
                                          const float* __restrict__ stats,
                                          float* __restrict__ partial,
                                          int sub, int ksi, SM& sm)
{
  constexpr int PAD = (KS - 1) / 2;
  constexpr float C1f = (float)(0.01 * 0.01);
  constexpr float C2f = (float)(0.03 * 0.03);

  const int img = sub >> 3;
  const int band = sub & 7;
  const int t = threadIdx.x;

  // gaussian weights in double to match numpy
  if (t < 5) {
    const double sigs[5] = {0.8, 1.2, 1.5, 1.8, 2.0};
    double sig = sigs[t];
    double tmp[KS]; double sum = 0.0;
    #pragma unroll
    for (int a = 0; a < KS; ++a) {
      double d = (double)(a - PAD) / sig;
      double e = exp(-0.5 * d * d);
      tmp[a] = e; sum += e;
    }
    #pragma unroll
    for (int a = 0; a < KS; ++a) sm.gw[t][a] = (float)(tmp[a] / sum);
  }

  const float mx = stats[(0*NIMG + img)*2 + 0];
  const float ix = stats[(0*NIMG + img)*2 + 1];
  const float my = stats[(1*NIMG + img)*2 + 0];
  const float iy = stats[(1*NIMG + img)*2 + 1];

  const float4* p4 = (const float4*)(pred + (size_t)img * NPX);
  const float4* t4 = (const float4*)(targ + (size_t)img * NPX);

  float acc = 0.f;

  for (int st = 0; st < 2; ++st) {
    const int r0 = band*32 + st*16;        // output rows r0 .. r0+15
    __syncthreads();                       // xy reuse + gw visibility
    // stage rows r0-6 .. r0+21 (28 rows, reflect), standardized, bf16-packed
    for (int i = t; i < 28*64; i += 256) {
      const int row = i >> 6, c4 = i & 63;
      const int gr = refl_idx(r0 - 6 + row);
      float4 a = p4[gr*64 + c4];
      float4 b = t4[gr*64 + c4];
      uint4 o;
      o.x = packxy((a.x - mx)*ix, (b.x - my)*iy);
      o.y = packxy((a.y - mx)*ix, (b.y - my)*iy);
      o.z = packxy((a.z - mx)*ix, (b.z - my)*iy);
      o.w = packxy((a.w - mx)*ix, (b.w - my)*iy);
      *(uint4*)&sm.xy[row][c4*4] = o;
    }
    __syncthreads();

    for (int si = 0; si < 5; ++si) {
      float g[KS];
      #pragma unroll
      for (int a = 0; a < KS; ++a) g[a] = sm.gw[si][a];

      for (int ch = 0; ch < 4; ++ch) {
        // ---- vertical pass: thread = logical col, 4 output rows ----
        for (int cc = t - 8; cc < 264; cc += 256) {
          const int rc = cc < 0 ? -cc : (cc > 255 ? 510 - cc : cc);
          float amx[4] = {0,0,0,0}, amy[4] = {0,0,0,0};
          float axx[4] = {0,0,0,0}, ayy[4] = {0,0,0,0}, axy[4] = {0,0,0,0};
          const int base = ch*4 + 6 - PAD;   // xy row index of (rr=0, tap a=0)
          #pragma unroll
          for (int i2 = 0; i2 < KS + 3; ++i2) {
            const unsigned int u = sm.xy[base + i2][rc];
            const float xv = __uint_as_float(u << 16);
            const float yv = __uint_as_float(u & 0xffff0000u);
            const float xx = xv*xv, yy = yv*yv, xyv = xv*yv;
            #pragma unroll
            for (int rr = 0; rr < 4; ++rr) {
              const int a = i2 - rr;
              if (a >= 0 && a < KS) {
                amx[rr] += g[a]*xv; amy[rr] += g[a]*yv;
                axx[rr] += g[a]*xx; ayy[rr] += g[a]*yy; axy[rr] += g[a]*xyv;
              }
            }
          }
          #pragma unroll
          for (int rr = 0; rr < 4; ++rr) {
            sm.vf[0][rr][cc+8] = amx[rr]; sm.vf[1][rr][cc+8] = amy[rr];
            sm.vf[2][rr][cc+8] = axx[rr]; sm.vf[3][rr][cc+8] = ayy[rr];
            sm.vf[4][rr][cc+8] = axy[rr];
          }
        }
        __syncthreads();

        // ---- horizontal pass + smap: thread = (row rr, 4 consecutive cols) ----
        {
          const int rr = t >> 6;
          const int c0 = (t & 63) * 4;
          const int r  = r0 + ch*4 + rr;
          float h[5][4];
          #pragma unroll
          for (int f = 0; f < 5; ++f) {
            float wv[20];
            #pragma unroll
            for (int j = 0; j < 5; ++j) {
              if (j >= (8 - PAD)/4 && j <= (11 + PAD)/4) {
                const float4 v = *(const float4*)&sm.vf[f][rr][c0 + 4*j];
                wv[4*j+0] = v.x; wv[4*j+1] = v.y; wv[4*j+2] = v.z; wv[4*j+3] = v.w;
              }
            }
            #pragma unroll
            for (int p = 0; p < 4; ++p) {
              float s = 0.f;
              #pragma unroll
              for (int b = 0; b < KS; ++b)
                s += g[b] * wv[8 - PAD + p + b];
              h[f][p] = s;
            }
          }
          const bool rok = (r >= PAD) && (r < HW - PAD);
          #pragma unroll
          for (int p = 0; p < 4; ++p) {
            const int c = c0 + p;
            if (rok && c >= PAD && c < HW - PAD) {
              const float hx = h[0][p], hy = h[1][p];
              const float hxx = h[2][p], hyy = h[3][p], hxy = h[4][p];
              const float sx = hxx - hx*hx, sy = hyy - hy*hy, sxy = hxy - hx*hy;
              const float num = (2.f*hx*hy + C1f) * (2.f*sxy + C2f);
              const float den = (hx*hx + hy*hy + C1f) * (sx + sy + C2f);
              acc += num / den;
            }
          }
        }
        __syncthreads();
      } // ch
    } // si
  } // st

  sm.red[t] = acc;
  __syncthreads();
  for (int off = 128; off > 0; off >>= 1) {
    if (t < off) sm.red[t] += sm.red[t+off];
    __syncthreads();
  }
  if (t == 0) {
    constexpr float npix = (float)((HW - 2*PAD) * (HW - 2*PAD));
    partial[ksi*1024 + sub] = sm.red[0] / (npix * 25.f * 128.f);
  }
}

__global__ __launch_bounds__(256, 3)
void ssim_merged(const float* __restrict__ pred, const float* __restrict__ targ,
                 const float* __restrict__ stats, float* __restrict__ partial)
{
  __shared__ SM sm;
  const int bid = blockIdx.x;
  const int ksi = bid % 5;     // block-uniform
  const int sub = bid / 5;
  switch (ksi) {
    case 0: ssim_body<13>(pred, targ, stats, partial, sub, 0, sm); break;
    case 1: ssim_body<11>(pred, targ, stats, partial, sub, 1, sm); break;
    case 2: ssim_body<9> (pred, targ, stats, partial, sub, 2, sm); break;
    case 3: ssim_body<7> (pred, targ, stats, partial, sub, 3, sm); break;
    case 4: ssim_body<5> (pred, targ, stats, partial, sub, 4, sm); break;
  }
}

// ---------------- Kernel C: final deterministic reduction ----------------
__global__ __launch_bounds__(256)
void reduce_kernel(const float* __restrict__ partial, float* __restrict__ out)
{
  const int t = threadIdx.x;
  double s = 0.0;
  for (int i = t; i < 5*1024; i += 256) s += (double)partial[i];
  __shared__ double red[256];
  red[t] = s;
  __syncthreads();
  for (int off = 128; off > 0; off >>= 1) {
    if (t < off) red[t] += red[t+off];
    __syncthreads();
  }
  if (t == 0) out[0] = (float)(0.5 - 0.5 * red[0]);
}

extern "C" void kernel_launch(void* const* d_in, const int* in_sizes, int n_in,
                              void* d_out, int out_size, void* d_ws, size_t ws_size,
                              hipStream_t stream) {
  const float* pred = (const float*)d_in[0];
  const float* targ = (const float*)d_in[1];
  float* out = (float*)d_out;
  float* ws = (float*)d_ws;
  float* stats   = ws;          // 512 floats
  float* partial = ws + 512;    // 5*1024 floats

  stats_kernel<<<256, 256, 0, stream>>>(pred, targ, stats);
  ssim_merged<<<5120, 256, 0, stream>>>(pred, targ, stats, partial);
  reduce_kernel<<<1, 256, 0, stream>>>(partial, out);
}

// Round 7
// 1002.367 us; speedup vs baseline: 2.7782x; 1.4061x over previous
//
#include <hip/hip_runtime.h>
#include <math.h>

#define NIMG 128
#define HW   256
#define NPX  (HW*HW)
#define NBLK (5*5*NIMG*16)   // 51200 blocks: (ks, sigma, img, strip)

typedef float f32x4 __attribute__((ext_vector_type(4)));
typedef short bf16x8 __attribute__((ext_vector_type(8)));

__device__ __forceinline__ int refl_idx(int t) {
  return t < 0 ? -t : (t > 255 ? 510 - t : t);
}
__device__ __forceinline__ unsigned int bf16_rtn(float f) {
  unsigned int u = __float_as_uint(f);
  return (u + 0x7fffu + ((u >> 16) & 1u)) >> 16;
}
__device__ __forceinline__ unsigned int packxy(float x, float y) {
  return bf16_rtn(x) | (bf16_rtn(y) << 16);
}
// round-half-up (magnitude) bf16 pack of two floats -> u32; cheap, ~unbiased
__device__ __forceinline__ unsigned int rhu_pack(float a, float b) {
  return ((__float_as_uint(a) + 0x8000u) >> 16) |
         ((__float_as_uint(b) + 0x8000u) & 0xffff0000u);
}
__device__ __forceinline__ unsigned short bf16_rhu(float a) {
  return (unsigned short)((__float_as_uint(a) + 0x8000u) >> 16);
}

// ---------------- Kernel A: per-image mean / inv_std (ddof=1) ----------------
__global__ __launch_bounds__(256)
void stats_kernel(const float* __restrict__ pred, const float* __restrict__ targ,
                  float* __restrict__ stats)
{
  const int b = blockIdx.x;        // 0..255
  const int which = b >> 7;        // 0 pred, 1 targ
  const int img = b & 127;
  const float4* src = (const float4*)((which ? targ : pred) + (size_t)img * NPX);
  const int t = threadIdx.x;
  double s = 0.0, s2 = 0.0;
  for (int i = t; i < NPX/4; i += 256) {
    float4 v = src[i];
    s  += (double)v.x + (double)v.y + (double)v.z + (double)v.w;
    s2 += (double)v.x*v.x + (double)v.y*v.y + (double)v.z*v.z + (double)v.w*v.w;
  }
  __shared__ double rs[256], rs2[256];
  rs[t] = s; rs2[t] = s2;
  __syncthreads();
  for (int off = 128; off > 0; off >>= 1) {
    if (t < off) { rs[t] += rs[t+off]; rs2[t] += rs2[t+off]; }
    __syncthreads();
  }
  if (t == 0) {
    const double n = (double)NPX;
    double mean = rs[0] / n;
    double var = (rs2[0] - n*mean*mean) / (n - 1.0);
    stats[(which*NIMG + img)*2 + 0] = (float)mean;
    stats[(which*NIMG + img)*2 + 1] = (float)(1.0 / sqrt(var));
  }
}

// ---------------- MFMA SSIM kernel ----------------
// One block = one (ks, sigma, img, 16-row strip). 256 threads = 4 waves.
// Both separable blur passes are banded 16x16x32 bf16 MFMAs sharing one
// weight fragment (band d = k - m - 6 + PAD identical for both passes).
// LDS: plane (x,y packed, stride 257 -> conflict-free column reads) 32.9KB
//      vfT (5 fields, 16 rows, stride 282 -> <=2-way) 45.1KB   total 79.2KB
__global__ __launch_bounds__(256, 2)
void ssim_mfma(const float* __restrict__ pred, const float* __restrict__ targ,
               const float* __restrict__ stats, float* __restrict__ partial)
{
  __shared__ unsigned int plane[32*257];        // staged rows: x|y<<16 bf16
  __shared__ unsigned short vfT[5*16*282];      // vertical-blur fields, bf16
  __shared__ double gwd[16];
  __shared__ float gwf[16];
  __shared__ float red[256];

  const int bid = blockIdx.x;
  const int c5  = bid % 25;
  const int ksi = c5 / 5, si = c5 % 5;
  const int sub = bid / 25;
  const int img = sub >> 4, strip = sub & 15;
  const int R0  = strip * 16;
  const int t = threadIdx.x;
  const int lane = t & 63, wid = t >> 6;
  const int g = lane >> 4;        // k-group 0..3
  const int mrow = lane & 15;     // A-row / B-col lane index

  const int KS_LIST[5] = {5,7,9,11,13};
  const int ks  = KS_LIST[ksi];
  const int PAD = (ks - 1) >> 1;

  // --- gaussian weights (double, numpy-matching), taps by threads 0..15 ---
  if (t < 16) {
    const double sigs[5] = {0.8, 1.2, 1.5, 1.8, 2.0};
    double d = (double)(t - PAD) / sigs[si];
    gwd[t] = (t < ks) ? exp(-0.5 * d * d) : 0.0;
  }
  // --- zero vfT pad cols 272..281 (never overwritten; horizontal reads w/ W=0) ---
  for (int i = t; i < 5*16*10; i += 256) {
    int rowf = i / 10, cp = 272 + (i % 10);
    vfT[rowf*282 + cp] = 0;
  }
  // --- stage 32 reflected rows (R0-6 .. R0+25), standardized, bf16-packed ---
  const float mx = stats[img*2 + 0];
  const float ixv = stats[img*2 + 1];
  const float my = stats[(NIMG + img)*2 + 0];
  const float iyv = stats[(NIMG + img)*2 + 1];
  const float4* p4 = (const float4*)(pred + (size_t)img * NPX);
  const float4* t4 = (const float4*)(targ + (size_t)img * NPX);
  for (int i = t; i < 32*64; i += 256) {
    int row = i >> 6, c4 = i & 63;
    int gr = refl_idx(R0 - 6 + row);
    float4 a = p4[gr*64 + c4];
    float4 b = t4[gr*64 + c4];
    int base = row*257 + c4*4;
    plane[base+0] = packxy((a.x-mx)*ixv, (b.x-my)*iyv);
    plane[base+1] = packxy((a.y-mx)*ixv, (b.y-my)*iyv);
    plane[base+2] = packxy((a.z-mx)*ixv, (b.z-my)*iyv);
    plane[base+3] = packxy((a.w-mx)*ixv, (b.w-my)*iyv);
  }
  __syncthreads();
  if (t < 16) {
    double s = 0.0;
    #pragma unroll
    for (int a2 = 0; a2 < 16; ++a2) s += gwd[a2];
    gwf[t] = (float)(gwd[t] / s);
  }
  __syncthreads();

  // --- weight fragment A[m][k] = g[k - m - 6 + PAD], k = g*8 + elem ---
  union UF { unsigned int w[4]; bf16x8 v; };
  UF ua_;
  #pragma unroll
  for (int j2 = 0; j2 < 4; ++j2) {
    int k0 = g*8 + 2*j2;
    int d0 = k0 - mrow - 6 + PAD;
    int d1 = d0 + 1;
    float w0 = (d0 >= 0 && d0 < ks) ? gwf[d0] : 0.f;
    float w1 = (d1 >= 0 && d1 < ks) ? gwf[d1] : 0.f;
    ua_.w[j2] = bf16_rtn(w0) | (bf16_rtn(w1) << 16);
  }
  const bf16x8 afrag = ua_.v;
  const f32x4 zero4 = {0.f, 0.f, 0.f, 0.f};

  // --- vertical pass: 17 col-tiles over vc 0..271 (image col = vc-8, reflect) ---
  for (int tau = wid; tau < 17; tau += 4) {
    int vc = tau*16 + mrow;
    int ic = refl_idx(vc - 8);
    unsigned int u[8];
    #pragma unroll
    for (int j = 0; j < 8; ++j) u[j] = plane[(g*8 + j)*257 + ic];
    UF fx, fy, fxx, fyy, fxy;
    #pragma unroll
    for (int j2 = 0; j2 < 4; ++j2) {
      unsigned int a0 = u[2*j2], b0 = u[2*j2+1];
      fx.w[j2] = (a0 & 0xffffu) | (b0 << 16);
      fy.w[j2] = (a0 >> 16) | (b0 & 0xffff0000u);
      float xa = __uint_as_float(a0 << 16), ya = __uint_as_float(a0 & 0xffff0000u);
      float xb = __uint_as_float(b0 << 16), yb = __uint_as_float(b0 & 0xffff0000u);
      fxx.w[j2] = rhu_pack(xa*xa, xb*xb);
      fyy.w[j2] = rhu_pack(ya*ya, yb*yb);
      fxy.w[j2] = rhu_pack(xa*ya, xb*yb);
    }
    f32x4 dx  = __builtin_amdgcn_mfma_f32_16x16x32_bf16(afrag, fx.v,  zero4, 0,0,0);
    f32x4 dy  = __builtin_amdgcn_mfma_f32_16x16x32_bf16(afrag, fy.v,  zero4, 0,0,0);
    f32x4 dxx = __builtin_amdgcn_mfma_f32_16x16x32_bf16(afrag, fxx.v, zero4, 0,0,0);
    f32x4 dyy = __builtin_amdgcn_mfma_f32_16x16x32_bf16(afrag, fyy.v, zero4, 0,0,0);
    f32x4 dxy = __builtin_amdgcn_mfma_f32_16x16x32_bf16(afrag, fxy.v, zero4, 0,0,0);
    #pragma unroll
    for (int i = 0; i < 4; ++i) {
      int rb = (g*4 + i)*282 + vc;     // D row = (lane>>4)*4 + reg, col = lane&15
      vfT[0*4512 + rb] = bf16_rhu(dx[i]);
      vfT[1*4512 + rb] = bf16_rhu(dy[i]);
      vfT[2*4512 + rb] = bf16_rhu(dxx[i]);
      vfT[3*4512 + rb] = bf16_rhu(dyy[i]);
      vfT[4*4512 + rb] = bf16_rhu(dxy[i]);
    }
  }
  __syncthreads();

  // --- horizontal pass + smap: 16 out-col tiles; A reused; B = vfT window ---
  float acc = 0.f;
  const float C1f = 1e-4f, C2f = 9e-4f;
  const unsigned int* vfT32 = (const unsigned int*)vfT;
  const int r = R0 + mrow;
  const bool rok = (r >= PAD) && (r < HW - PAD);
  for (int ht = wid; ht < 16; ht += 4) {
    int C0 = ht*16;
    int KBh = (C0 + 2) >> 1;              // window base vc = C0+2 (even), halfword/2
    UF bx, by, bxx, byy, bxy;
    int w0 = mrow*141 + KBh + g*4;        // (f*16+row)*282/2 terms; field stride 2256
    #pragma unroll
    for (int j2 = 0; j2 < 4; ++j2) {
      bx.w[j2]  = vfT32[w0 + j2];
      by.w[j2]  = vfT32[w0 + j2 + 2256];
      bxx.w[j2] = vfT32[w0 + j2 + 2*2256];
      byy.w[j2] = vfT32[w0 + j2 + 3*2256];
      bxy.w[j2] = vfT32[w0 + j2 + 4*2256];
    }
    f32x4 dhx  = __builtin_amdgcn_mfma_f32_16x16x32_bf16(afrag, bx.v,  zero4, 0,0,0);
    f32x4 dhy  = __builtin_amdgcn_mfma_f32_16x16x32_bf16(afrag, by.v,  zero4, 0,0,0);
    f32x4 dhxx = __builtin_amdgcn_mfma_f32_16x16x32_bf16(afrag, bxx.v, zero4, 0,0,0);
    f32x4 dhyy = __builtin_amdgcn_mfma_f32_16x16x32_bf16(afrag, byy.v, zero4, 0,0,0);
    f32x4 dhxy = __builtin_amdgcn_mfma_f32_16x16x32_bf16(afrag, bxy.v, zero4, 0,0,0);
    #pragma unroll
    for (int i = 0; i < 4; ++i) {
      int c = C0 + g*4 + i;               // D row = out-col, D col = strip row
      if (rok && c >= PAD && c < HW - PAD) {
        float hx = dhx[i], hy = dhy[i];
        float hxx = dhxx[i], hyy = dhyy[i], hxy = dhxy[i];
        float sx = hxx - hx*hx, sy = hyy - hy*hy, sxy = hxy - hx*hy;
        float num = (2.f*hx*hy + C1f) * (2.f*sxy + C2f);
        float den = (hx*hx + hy*hy + C1f) * (sx + sy + C2f);
        acc += num / den;
      }
    }
  }

  // --- block reduction ---
  red[t] = acc;
  __syncthreads();
  for (int off = 128; off > 0; off >>= 1) {
    if (t < off) red[t] += red[t+off];
    __syncthreads();
  }
  if (t == 0) {
    float npix = (float)((HW - 2*PAD) * (HW - 2*PAD));
    partial[bid] = red[0] / (npix * 25.f * 128.f);
  }
}

// ---------------- Kernel C: final deterministic reduction ----------------
__global__ __launch_bounds__(256)
void reduce_kernel(const float* __restrict__ partial, float* __restrict__ out)
{
  const int t = threadIdx.x;
  double s = 0.0;
  for (int i = t; i < NBLK; i += 256) s += (double)partial[i];
  __shared__ double red[256];
  red[t] = s;
  __syncthreads();
  for (int off = 128; off > 0; off >>= 1) {
    if (t < off) red[t] += red[t+off];
    __syncthreads();
  }
  if (t == 0) out[0] = (float)(0.5 - 0.5 * red[0]);
}

extern "C" void kernel_launch(void* const* d_in, const int* in_sizes, int n_in,
                              void* d_out, int out_size, void* d_ws, size_t ws_size,
                              hipStream_t stream) {
  const float* pred = (const float*)d_in[0];
  const float* targ = (const float*)d_in[1];
  float* out = (float*)d_out;
  float* ws = (float*)d_ws;
  float* stats   = ws;          // 512 floats
  float* partial = ws + 512;    // NBLK floats

  stats_kernel<<<256, 256, 0, stream>>>(pred, targ, stats);
  ssim_mfma<<<NBLK, 256, 0, stream>>>(pred, targ, stats, partial);
  reduce_kernel<<<1, 256, 0, stream>>>(partial, out);
}

// Round 8
// 613.077 us; speedup vs baseline: 4.5423x; 1.6350x over previous
//
#include <hip/hip_runtime.h>
#include <math.h>

#define NIMG 128
#define HW   256
#define NPX  (HW*HW)
#define NBLK (NIMG*16)   // 2048 blocks: (img, strip)

typedef float f32x4 __attribute__((ext_vector_type(4)));
typedef short bf16x8 __attribute__((ext_vector_type(8)));

__device__ __forceinline__ int refl_idx(int t) {
  return t < 0 ? -t : (t > 255 ? 510 - t : t);
}
__device__ __forceinline__ unsigned int bf16_rtn(float f) {
  unsigned int u = __float_as_uint(f);
  return (u + 0x7fffu + ((u >> 16) & 1u)) >> 16;
}
// pack two floats as bf16 (round-nearest-even): lo=a, hi=b
__device__ __forceinline__ unsigned int rtn_pack(float a, float b) {
  return bf16_rtn(a) | (bf16_rtn(b) << 16);
}
// round-half-up bf16 pack (cheap, ~unbiased)
__device__ __forceinline__ unsigned int rhu_pack(float a, float b) {
  return ((__float_as_uint(a) + 0x8000u) >> 16) |
         ((__float_as_uint(b) + 0x8000u) & 0xffff0000u);
}
__device__ __forceinline__ unsigned short bf16_rhu(float a) {
  return (unsigned short)((__float_as_uint(a) + 0x8000u) >> 16);
}

// ---------------- Kernel A: per-image mean / inv_std (ddof=1) ----------------
__global__ __launch_bounds__(256)
void stats_kernel(const float* __restrict__ pred, const float* __restrict__ targ,
                  float* __restrict__ stats)
{
  const int b = blockIdx.x;        // 0..255
  const int which = b >> 7;
  const int img = b & 127;
  const float4* src = (const float4*)((which ? targ : pred) + (size_t)img * NPX);
  const int t = threadIdx.x;
  double s = 0.0, s2 = 0.0;
  for (int i = t; i < NPX/4; i += 256) {
    float4 v = src[i];
    s  += (double)v.x + (double)v.y + (double)v.z + (double)v.w;
    s2 += (double)v.x*v.x + (double)v.y*v.y + (double)v.z*v.z + (double)v.w*v.w;
  }
  __shared__ double rs[256], rs2[256];
  rs[t] = s; rs2[t] = s2;
  __syncthreads();
  for (int off = 128; off > 0; off >>= 1) {
    if (t < off) { rs[t] += rs[t+off]; rs2[t] += rs2[t+off]; }
    __syncthreads();
  }
  if (t == 0) {
    const double n = (double)NPX;
    double mean = rs[0] / n;
    double var = (rs2[0] - n*mean*mean) / (n - 1.0);
    stats[(which*NIMG + img)*2 + 0] = (float)mean;
    stats[(which*NIMG + img)*2 + 1] = (float)(1.0 / sqrt(var));
  }
}

// ---------------- Fused SSIM kernel: all 25 combos per block ----------------
// Block = (img, strip of 16 out rows). 512 threads = 8 waves. Stage the five
// combo-invariant fields ONCE (bf16 pairs, MFMA-ready, reflect baked in),
// then loop 25 (ks,sigma) combos: banded-W vertical MFMA -> vfT -> banded-W
// horizontal MFMA -> smap. LDS ~132KB -> 1 block/CU, 2 waves/SIMD.
struct SMEM {
  unsigned int fields[5][16][272];   // 87040 B: [field][k-pair][col] (bf16 lo=row2k, hi=row2k+1)
  unsigned short vfT[5*16*282];      // 45120 B: vertical-blur out, bf16 [field][row][col]
  unsigned short gwb[25][16];        // 800 B: bf16 gaussian taps per combo
  float red[512];                    // 2048 B
};

__global__ __launch_bounds__(512, 2)
void ssim_fused(const float* __restrict__ pred, const float* __restrict__ targ,
                const float* __restrict__ stats, float* __restrict__ partial)
{
  __shared__ SMEM sm;
  const int bid = blockIdx.x;
  const int img = bid >> 4, strip = bid & 15;
  const int R0 = strip * 16;
  const int t = threadIdx.x;
  const int lane = t & 63, wid = t >> 6;
  const int g = lane >> 4;        // k-group 0..3
  const int mrow = lane & 15;     // A-row / B-col lane index

  // --- phase 0: all 25 combos' bf16 weight taps (double math, numpy-matching) ---
  if (t < 400) {
    const int c = t >> 4, tap = t & 15;
    const int ksi = c / 5, si = c % 5;
    const int ks = 5 + 2*ksi, PAD = 2 + ksi;
    const double sig = (si==0)?0.8:(si==1)?1.2:(si==2)?1.5:(si==3)?1.8:2.0;
    unsigned short w = 0;
    if (tap < ks) {
      double sum = 0.0, mine = 0.0;
      for (int a = 0; a < ks; ++a) {
        double d = (double)(a - PAD) / sig;
        double e = exp(-0.5 * d * d);
        sum += e;
        if (a == tap) mine = e;
      }
      w = (unsigned short)bf16_rtn((float)(mine / sum));
    }
    sm.gwb[c][tap] = w;
  }

  // --- phase 1: stage fields directly (rows R0-6..R0+25 as 16 pairs, cols -8..263) ---
  const float mx  = stats[img*2 + 0];
  const float ixv = stats[img*2 + 1];
  const float my  = stats[(NIMG + img)*2 + 0];
  const float iyv = stats[(NIMG + img)*2 + 1];
  const float4* p4 = (const float4*)(pred + (size_t)img * NPX);
  const float4* t4 = (const float4*)(targ + (size_t)img * NPX);

  for (int i = t; i < 16*64; i += 512) {
    const int k2 = i >> 6, c4 = i & 63;
    const int gr0 = refl_idx(R0 - 6 + 2*k2);
    const int gr1 = refl_idx(R0 - 6 + 2*k2 + 1);
    float4 pa = p4[gr0*64 + c4], pb = p4[gr1*64 + c4];
    float4 ta = t4[gr0*64 + c4], tb = t4[gr1*64 + c4];
    uint4 wx, wy, wxx, wyy, wxy;
    {
      float xa=(pa.x-mx)*ixv, xb=(pb.x-mx)*ixv, ya=(ta.x-my)*iyv, yb=(tb.x-my)*iyv;
      wx.x = rtn_pack(xa, xb); wy.x = rtn_pack(ya, yb);
      wxx.x = rhu_pack(xa*xa, xb*xb); wyy.x = rhu_pack(ya*ya, yb*yb); wxy.x = rhu_pack(xa*ya, xb*yb);
    }
    {
      float xa=(pa.y-mx)*ixv, xb=(pb.y-mx)*ixv, ya=(ta.y-my)*iyv, yb=(tb.y-my)*iyv;
      wx.y = rtn_pack(xa, xb); wy.y = rtn_pack(ya, yb);
      wxx.y = rhu_pack(xa*xa, xb*xb); wyy.y = rhu_pack(ya*ya, yb*yb); wxy.y = rhu_pack(xa*ya, xb*yb);
    }
    {
      float xa=(pa.z-mx)*ixv, xb=(pb.z-mx)*ixv, ya=(ta.z-my)*iyv, yb=(tb.z-my)*iyv;
      wx.z = rtn_pack(xa, xb); wy.z = rtn_pack(ya, yb);
      wxx.z = rhu_pack(xa*xa, xb*xb); wyy.z = rhu_pack(ya*ya, yb*yb); wxy.z = rhu_pack(xa*ya, xb*yb);
    }
    {
      float xa=(pa.w-mx)*ixv, xb=(pb.w-mx)*ixv, ya=(ta.w-my)*iyv, yb=(tb.w-my)*iyv;
      wx.w = rtn_pack(xa, xb); wy.w = rtn_pack(ya, yb);
      wxx.w = rhu_pack(xa*xa, xb*xb); wyy.w = rhu_pack(ya*ya, yb*yb); wxy.w = rhu_pack(xa*ya, xb*yb);
    }
    const int pc = 8 + c4*4;
    *(uint4*)&sm.fields[0][k2][pc] = wx;
    *(uint4*)&sm.fields[1][k2][pc] = wy;
    *(uint4*)&sm.fields[2][k2][pc] = wxx;
    *(uint4*)&sm.fields[3][k2][pc] = wyy;
    *(uint4*)&sm.fields[4][k2][pc] = wxy;
  }
  // reflect-pad columns (pc 0..7 and 264..271)
  if (t < 256) {
    const int k2 = t >> 4, j = t & 15;
    const int pc = (j < 8) ? j : 256 + j;
    const int ric = refl_idx(pc - 8);
    const int gr0 = refl_idx(R0 - 6 + 2*k2);
    const int gr1 = refl_idx(R0 - 6 + 2*k2 + 1);
    const float* pp = pred + (size_t)img * NPX;
    const float* tp = targ + (size_t)img * NPX;
    float xa = (pp[gr0*HW + ric] - mx)*ixv, xb = (pp[gr1*HW + ric] - mx)*ixv;
    float ya = (tp[gr0*HW + ric] - my)*iyv, yb = (tp[gr1*HW + ric] - my)*iyv;
    sm.fields[0][k2][pc] = rtn_pack(xa, xb);
    sm.fields[1][k2][pc] = rtn_pack(ya, yb);
    sm.fields[2][k2][pc] = rhu_pack(xa*xa, xb*xb);
    sm.fields[3][k2][pc] = rhu_pack(ya*ya, yb*yb);
    sm.fields[4][k2][pc] = rhu_pack(xa*ya, xb*yb);
  }
  // zero vfT pad cols 272..281 (never written by vertical pass)
  for (int i = t; i < 5*16*10; i += 512)
    sm.vfT[(i/10)*282 + 272 + (i%10)] = 0;

  union UF { unsigned int w[4]; bf16x8 v; };
  const f32x4 zero4 = {0.f, 0.f, 0.f, 0.f};
  const float C1f = 1e-4f, C2f = 9e-4f;
  float acc_total = 0.f;
  const int r = R0 + mrow;

  for (int cb = 0; cb < 25; ++cb) {
    const int ksi = cb / 5;
    const int ks = 5 + 2*ksi, PAD = 2 + ksi;

    __syncthreads();   // cb==0: fields/gwb/vfT-pads visible; cb>0: prev horizontal done

    // A fragment: A[m][k] = g[k - m - 6 + PAD] (shared by both passes)
    UF ua_;
    #pragma unroll
    for (int j2 = 0; j2 < 4; ++j2) {
      const int d0 = g*8 + 2*j2 - mrow - 6 + PAD;
      const unsigned int w0 = ((unsigned)d0 < 16u) ? (unsigned)sm.gwb[cb][d0] : 0u;
      const unsigned int w1 = ((unsigned)(d0+1) < 16u) ? (unsigned)sm.gwb[cb][d0+1] : 0u;
      ua_.w[j2] = w0 | (w1 << 16);
    }
    const bf16x8 afrag = ua_.v;

    // vertical pass: 17 col-tiles
    for (int tau = wid; tau < 17; tau += 8) {
      const int vc = tau*16 + mrow;
      UF bx, by, bxx, byy, bxy;
      #pragma unroll
      for (int j2 = 0; j2 < 4; ++j2) {
        bx.w[j2]  = sm.fields[0][g*4+j2][vc];
        by.w[j2]  = sm.fields[1][g*4+j2][vc];
        bxx.w[j2] = sm.fields[2][g*4+j2][vc];
        byy.w[j2] = sm.fields[3][g*4+j2][vc];
        bxy.w[j2] = sm.fields[4][g*4+j2][vc];
      }
      f32x4 dx  = __builtin_amdgcn_mfma_f32_16x16x32_bf16(afrag, bx.v,  zero4, 0,0,0);
      f32x4 dy  = __builtin_amdgcn_mfma_f32_16x16x32_bf16(afrag, by.v,  zero4, 0,0,0);
      f32x4 dxx = __builtin_amdgcn_mfma_f32_16x16x32_bf16(afrag, bxx.v, zero4, 0,0,0);
      f32x4 dyy = __builtin_amdgcn_mfma_f32_16x16x32_bf16(afrag, byy.v, zero4, 0,0,0);
      f32x4 dxy = __builtin_amdgcn_mfma_f32_16x16x32_bf16(afrag, bxy.v, zero4, 0,0,0);
      #pragma unroll
      for (int i = 0; i < 4; ++i) {
        const int rb = (g*4 + i)*282 + vc;
        sm.vfT[0*4512 + rb] = bf16_rhu(dx[i]);
        sm.vfT[1*4512 + rb] = bf16_rhu(dy[i]);
        sm.vfT[2*4512 + rb] = bf16_rhu(dxx[i]);
        sm.vfT[3*4512 + rb] = bf16_rhu(dyy[i]);
        sm.vfT[4*4512 + rb] = bf16_rhu(dxy[i]);
      }
    }
    __syncthreads();

    // horizontal pass + smap
    const unsigned int* vfT32 = (const unsigned int*)sm.vfT;
    const bool rok = (r >= PAD) && (r < HW - PAD);
    float accc = 0.f;
    for (int ht = wid; ht < 16; ht += 8) {
      const int C0 = ht*16;
      const int w0 = mrow*141 + ((C0 + 2) >> 1) + g*4;
      UF bx, by, bxx, byy, bxy;
      #pragma unroll
      for (int j2 = 0; j2 < 4; ++j2) {
        bx.w[j2]  = vfT32[w0 + j2];
        by.w[j2]  = vfT32[w0 + j2 + 2256];
        bxx.w[j2] = vfT32[w0 + j2 + 2*2256];
        byy.w[j2] = vfT32[w0 + j2 + 3*2256];
        bxy.w[j2] = vfT32[w0 + j2 + 4*2256];
      }
      f32x4 dhx  = __builtin_amdgcn_mfma_f32_16x16x32_bf16(afrag, bx.v,  zero4, 0,0,0);
      f32x4 dhy  = __builtin_amdgcn_mfma_f32_16x16x32_bf16(afrag, by.v,  zero4, 0,0,0);
      f32x4 dhxx = __builtin_amdgcn_mfma_f32_16x16x32_bf16(afrag, bxx.v, zero4, 0,0,0);
      f32x4 dhyy = __builtin_amdgcn_mfma_f32_16x16x32_bf16(afrag, byy.v, zero4, 0,0,0);
      f32x4 dhxy = __builtin_amdgcn_mfma_f32_16x16x32_bf16(afrag, bxy.v, zero4, 0,0,0);
      #pragma unroll
      for (int i = 0; i < 4; ++i) {
        const int c = C0 + g*4 + i;
        if (rok && c >= PAD && c < HW - PAD) {
          const float hx = dhx[i], hy = dhy[i];
          const float hxx = dhxx[i], hyy = dhyy[i], hxy = dhxy[i];
          const float sx = hxx - hx*hx, sy = hyy - hy*hy, sxy = hxy - hx*hy;
          const float num = (2.f*hx*hy + C1f) * (2.f*sxy + C2f);
          const float den = (hx*hx + hy*hy + C1f) * (sx + sy + C2f);
          accc += num * __builtin_amdgcn_rcpf(den);
        }
      }
    }
    const float n1 = (float)(HW - 2*PAD);
    acc_total += accc * __builtin_amdgcn_rcpf(n1 * n1);
  }

  // block reduction
  sm.red[t] = acc_total;
  __syncthreads();
  for (int off = 256; off > 0; off >>= 1) {
    if (t < off) sm.red[t] += sm.red[t+off];
    __syncthreads();
  }
  if (t == 0) partial[bid] = sm.red[0] * (1.f / (25.f * 128.f));
}

// ---------------- Kernel C: final deterministic reduction ----------------
__global__ __launch_bounds__(256)
void reduce_kernel(const float* __restrict__ partial, float* __restrict__ out)
{
  const int t = threadIdx.x;
  double s = 0.0;
  for (int i = t; i < NBLK; i += 256) s += (double)partial[i];
  __shared__ double red[256];
  red[t] = s;
  __syncthreads();
  for (int off = 128; off > 0; off >>= 1) {
    if (t < off) red[t] += red[t+off];
    __syncthreads();
  }
  if (t == 0) out[0] = (float)(0.5 - 0.5 * red[0]);
}

extern "C" void kernel_launch(void* const* d_in, const int* in_sizes, int n_in,
                              void* d_out, int out_size, void* d_ws, size_t ws_size,
                              hipStream_t stream) {
  const float* pred = (const float*)d_in[0];
  const float* targ = (const float*)d_in[1];
  float* out = (float*)d_out;
  float* ws = (float*)d_ws;
  float* stats   = ws;          // 512 floats
  float* partial = ws + 512;    // NBLK floats

  stats_kernel<<<256, 256, 0, stream>>>(pred, targ, stats);
  ssim_fused<<<NBLK, 512, 0, stream>>>(pred, targ, stats, partial);
  reduce_kernel<<<1, 256, 0, stream>>>(partial, out);
}

// Round 9
// 559.147 us; speedup vs baseline: 4.9804x; 1.0965x over previous
//
#include <hip/hip_runtime.h>
#include <math.h>

#define NIMG 128
#define HW   256
#define NPX  (HW*HW)
#define NBLK (NIMG*16)   // 2048 blocks: (img, strip)

typedef float f32x4 __attribute__((ext_vector_type(4)));
typedef short bf16x8 __attribute__((ext_vector_type(8)));

__device__ __forceinline__ int refl_idx(int t) {
  return t < 0 ? -t : (t > 255 ? 510 - t : t);
}
__device__ __forceinline__ unsigned int bf16_rtn(float f) {
  unsigned int u = __float_as_uint(f);
  return (u + 0x7fffu + ((u >> 16) & 1u)) >> 16;
}
// pack two floats as bf16 (round-nearest-even): lo=a, hi=b
__device__ __forceinline__ unsigned int rtn_pack(float a, float b) {
  return bf16_rtn(a) | (bf16_rtn(b) << 16);
}
// round-half-up bf16 pack (cheap, ~unbiased)
__device__ __forceinline__ unsigned int rhu_pack(float a, float b) {
  return ((__float_as_uint(a) + 0x8000u) >> 16) |
         ((__float_as_uint(b) + 0x8000u) & 0xffff0000u);
}
__device__ __forceinline__ unsigned short bf16_rhu(float a) {
  return (unsigned short)((__float_as_uint(a) + 0x8000u) >> 16);
}

// ---------------- Kernel A: per-image mean / inv_std (ddof=1) ----------------
__global__ __launch_bounds__(256)
void stats_kernel(const float* __restrict__ pred, const float* __restrict__ targ,
                  float* __restrict__ stats)
{
  const int b = blockIdx.x;        // 0..255
  const int which = b >> 7;
  const int img = b & 127;
  const float4* src = (const float4*)((which ? targ : pred) + (size_t)img * NPX);
  const int t = threadIdx.x;
  double s = 0.0, s2 = 0.0;
  for (int i = t; i < NPX/4; i += 256) {
    float4 v = src[i];
    s  += (double)v.x + (double)v.y + (double)v.z + (double)v.w;
    s2 += (double)v.x*v.x + (double)v.y*v.y + (double)v.z*v.z + (double)v.w*v.w;
  }
  __shared__ double rs[256], rs2[256];
  rs[t] = s; rs2[t] = s2;
  __syncthreads();
  for (int off = 128; off > 0; off >>= 1) {
    if (t < off) { rs[t] += rs[t+off]; rs2[t] += rs2[t+off]; }
    __syncthreads();
  }
  if (t == 0) {
    const double n = (double)NPX;
    double mean = rs[0] / n;
    double var = (rs2[0] - n*mean*mean) / (n - 1.0);
    stats[(which*NIMG + img)*2 + 0] = (float)mean;
    stats[(which*NIMG + img)*2 + 1] = (float)(1.0 / sqrt(var));
  }
}

// ---------------- Fused SSIM kernel: all 25 combos per block ----------------
// Block = (img, strip of 16 out rows). 1024 threads = 16 waves (4/SIMD,
// 50% occupancy cap) to hide LDS/VALU latency across the 50 barrier-split
// phases. Stage the five combo-invariant fields ONCE (bf16 pairs,
// MFMA-ready, reflect baked in), then loop 25 (ks,sigma) combos:
// banded-W vertical MFMA -> vfT -> banded-W horizontal MFMA -> smap.
// LDS ~137KB -> 1 block/CU.
struct SMEM {
  unsigned int fields[5][16][272];   // 87040 B: [field][k-pair][col] (bf16 lo=row2k, hi=row2k+1)
  unsigned short vfT[5*16*282];      // 45120 B: vertical-blur out, bf16 [field][row][col]
  unsigned short gwb[25][16];        // 800 B: bf16 gaussian taps per combo
  float red[1024];                   // 4096 B
};

__global__ __launch_bounds__(1024, 4)
void ssim_fused(const float* __restrict__ pred, const float* __restrict__ targ,
                const float* __restrict__ stats, float* __restrict__ partial)
{
  __shared__ SMEM sm;
  const int bid = blockIdx.x;
  const int img = bid >> 4, strip = bid & 15;
  const int R0 = strip * 16;
  const int t = threadIdx.x;
  const int lane = t & 63, wid = t >> 6;   // 16 waves
  const int g = lane >> 4;        // k-group 0..3
  const int mrow = lane & 15;     // A-row / B-col lane index

  // --- phase 0: all 25 combos' bf16 weight taps (double math, numpy-matching) ---
  if (t < 400) {
    const int c = t >> 4, tap = t & 15;
    const int ksi = c / 5, si = c % 5;
    const int ks = 5 + 2*ksi, PAD = 2 + ksi;
    const double sig = (si==0)?0.8:(si==1)?1.2:(si==2)?1.5:(si==3)?1.8:2.0;
    unsigned short w = 0;
    if (tap < ks) {
      double sum = 0.0, mine = 0.0;
      for (int a = 0; a < ks; ++a) {
        double d = (double)(a - PAD) / sig;
        double e = exp(-0.5 * d * d);
        sum += e;
        if (a == tap) mine = e;
      }
      w = (unsigned short)bf16_rtn((float)(mine / sum));
    }
    sm.gwb[c][tap] = w;
  }

  // --- phase 1: stage fields (rows R0-6..R0+25 as 16 pairs, cols -8..263) ---
  const float mx  = stats[img*2 + 0];
  const float ixv = stats[img*2 + 1];
  const float my  = stats[(NIMG + img)*2 + 0];
  const float iyv = stats[(NIMG + img)*2 + 1];
  const float4* p4 = (const float4*)(pred + (size_t)img * NPX);
  const float4* t4 = (const float4*)(targ + (size_t)img * NPX);

  {
    const int i = t;                 // exactly one iteration: 16*64 == 1024
    const int k2 = i >> 6, c4 = i & 63;
    const int gr0 = refl_idx(R0 - 6 + 2*k2);
    const int gr1 = refl_idx(R0 - 6 + 2*k2 + 1);
    float4 pa = p4[gr0*64 + c4], pb = p4[gr1*64 + c4];
    float4 ta = t4[gr0*64 + c4], tb = t4[gr1*64 + c4];
    uint4 wx, wy, wxx, wyy, wxy;
    {
      float xa=(pa.x-mx)*ixv, xb=(pb.x-mx)*ixv, ya=(ta.x-my)*iyv, yb=(tb.x-my)*iyv;
      wx.x = rtn_pack(xa, xb); wy.x = rtn_pack(ya, yb);
      wxx.x = rhu_pack(xa*xa, xb*xb); wyy.x = rhu_pack(ya*ya, yb*yb); wxy.x = rhu_pack(xa*ya, xb*yb);
    }
    {
      float xa=(pa.y-mx)*ixv, xb=(pb.y-mx)*ixv, ya=(ta.y-my)*iyv, yb=(tb.y-my)*iyv;
      wx.y = rtn_pack(xa, xb); wy.y = rtn_pack(ya, yb);
      wxx.y = rhu_pack(xa*xa, xb*xb); wyy.y = rhu_pack(ya*ya, yb*yb); wxy.y = rhu_pack(xa*ya, xb*yb);
    }
    {
      float xa=(pa.z-mx)*ixv, xb=(pb.z-mx)*ixv, ya=(ta.z-my)*iyv, yb=(tb.z-my)*iyv;
      wx.z = rtn_pack(xa, xb); wy.z = rtn_pack(ya, yb);
      wxx.z = rhu_pack(xa*xa, xb*xb); wyy.z = rhu_pack(ya*ya, yb*yb); wxy.z = rhu_pack(xa*ya, xb*yb);
    }
    {
      float xa=(pa.w-mx)*ixv, xb=(pb.w-mx)*ixv, ya=(ta.w-my)*iyv, yb=(tb.w-my)*iyv;
      wx.w = rtn_pack(xa, xb); wy.w = rtn_pack(ya, yb);
      wxx.w = rhu_pack(xa*xa, xb*xb); wyy.w = rhu_pack(ya*ya, yb*yb); wxy.w = rhu_pack(xa*ya, xb*yb);
    }
    const int pc = 8 + c4*4;
    *(uint4*)&sm.fields[0][k2][pc] = wx;
    *(uint4*)&sm.fields[1][k2][pc] = wy;
    *(uint4*)&sm.fields[2][k2][pc] = wxx;
    *(uint4*)&sm.fields[3][k2][pc] = wyy;
    *(uint4*)&sm.fields[4][k2][pc] = wxy;
  }
  // reflect-pad columns (pc 0..7 and 264..271)
  if (t < 256) {
    const int k2 = t >> 4, j = t & 15;
    const int pc = (j < 8) ? j : 256 + j;
    const int ric = refl_idx(pc - 8);
    const int gr0 = refl_idx(R0 - 6 + 2*k2);
    const int gr1 = refl_idx(R0 - 6 + 2*k2 + 1);
    const float* pp = pred + (size_t)img * NPX;
    const float* tp = targ + (size_t)img * NPX;
    float xa = (pp[gr0*HW + ric] - mx)*ixv, xb = (pp[gr1*HW + ric] - mx)*ixv;
    float ya = (tp[gr0*HW + ric] - my)*iyv, yb = (tp[gr1*HW + ric] - my)*iyv;
    sm.fields[0][k2][pc] = rtn_pack(xa, xb);
    sm.fields[1][k2][pc] = rtn_pack(ya, yb);
    sm.fields[2][k2][pc] = rhu_pack(xa*xa, xb*xb);
    sm.fields[3][k2][pc] = rhu_pack(ya*ya, yb*yb);
    sm.fields[4][k2][pc] = rhu_pack(xa*ya, xb*yb);
  }
  // zero vfT pad cols 272..281 (never written by vertical pass)
  if (t < 800)
    sm.vfT[(t/10)*282 + 272 + (t%10)] = 0;

  union UF { unsigned int w[4]; bf16x8 v; };
  const f32x4 zero4 = {0.f, 0.f, 0.f, 0.f};
  const float C1f = 1e-4f, C2f = 9e-4f;
  float acc_total = 0.f;
  const int r = R0 + mrow;

  for (int cb = 0; cb < 25; ++cb) {
    const int ksi = cb / 5;
    const int ks = 5 + 2*ksi, PAD = 2 + ksi;

    __syncthreads();   // cb==0: fields/gwb/vfT-pads visible; cb>0: prev horizontal done

    // A fragment: A[m][k] = g[k - m - 6 + PAD] (shared by both passes)
    UF ua_;
    #pragma unroll
    for (int j2 = 0; j2 < 4; ++j2) {
      const int d0 = g*8 + 2*j2 - mrow - 6 + PAD;
      const unsigned int w0 = ((unsigned)d0 < 16u) ? (unsigned)sm.gwb[cb][d0] : 0u;
      const unsigned int w1 = ((unsigned)(d0+1) < 16u) ? (unsigned)sm.gwb[cb][d0+1] : 0u;
      ua_.w[j2] = w0 | (w1 << 16);
    }
    const bf16x8 afrag = ua_.v;

    // vertical pass: 17 col-tiles over 16 waves
    for (int tau = wid; tau < 17; tau += 16) {
      const int vc = tau*16 + mrow;
      UF bx, by, bxx, byy, bxy;
      #pragma unroll
      for (int j2 = 0; j2 < 4; ++j2) {
        bx.w[j2]  = sm.fields[0][g*4+j2][vc];
        by.w[j2]  = sm.fields[1][g*4+j2][vc];
        bxx.w[j2] = sm.fields[2][g*4+j2][vc];
        byy.w[j2] = sm.fields[3][g*4+j2][vc];
        bxy.w[j2] = sm.fields[4][g*4+j2][vc];
      }
      f32x4 dx  = __builtin_amdgcn_mfma_f32_16x16x32_bf16(afrag, bx.v,  zero4, 0,0,0);
      f32x4 dy  = __builtin_amdgcn_mfma_f32_16x16x32_bf16(afrag, by.v,  zero4, 0,0,0);
      f32x4 dxx = __builtin_amdgcn_mfma_f32_16x16x32_bf16(afrag, bxx.v, zero4, 0,0,0);
      f32x4 dyy = __builtin_amdgcn_mfma_f32_16x16x32_bf16(afrag, byy.v, zero4, 0,0,0);
      f32x4 dxy = __builtin_amdgcn_mfma_f32_16x16x32_bf16(afrag, bxy.v, zero4, 0,0,0);
      #pragma unroll
      for (int i = 0; i < 4; ++i) {
        const int rb = (g*4 + i)*282 + vc;
        sm.vfT[0*4512 + rb] = bf16_rhu(dx[i]);
        sm.vfT[1*4512 + rb] = bf16_rhu(dy[i]);
        sm.vfT[2*4512 + rb] = bf16_rhu(dxx[i]);
        sm.vfT[3*4512 + rb] = bf16_rhu(dyy[i]);
        sm.vfT[4*4512 + rb] = bf16_rhu(dxy[i]);
      }
    }
    __syncthreads();

    // horizontal pass + smap: exactly one 16-col tile per wave
    {
      const unsigned int* vfT32 = (const unsigned int*)sm.vfT;
      const bool rok = (r >= PAD) && (r < HW - PAD);
      float accc = 0.f;
      const int ht = wid;
      const int C0 = ht*16;
      const int w0 = mrow*141 + ((C0 + 2) >> 1) + g*4;
      UF bx, by, bxx, byy, bxy;
      #pragma unroll
      for (int j2 = 0; j2 < 4; ++j2) {
        bx.w[j2]  = vfT32[w0 + j2];
        by.w[j2]  = vfT32[w0 + j2 + 2256];
        bxx.w[j2] = vfT32[w0 + j2 + 2*2256];
        byy.w[j2] = vfT32[w0 + j2 + 3*2256];
        bxy.w[j2] = vfT32[w0 + j2 + 4*2256];
      }
      f32x4 dhx  = __builtin_amdgcn_mfma_f32_16x16x32_bf16(afrag, bx.v,  zero4, 0,0,0);
      f32x4 dhy  = __builtin_amdgcn_mfma_f32_16x16x32_bf16(afrag, by.v,  zero4, 0,0,0);
      f32x4 dhxx = __builtin_amdgcn_mfma_f32_16x16x32_bf16(afrag, bxx.v, zero4, 0,0,0);
      f32x4 dhyy = __builtin_amdgcn_mfma_f32_16x16x32_bf16(afrag, byy.v, zero4, 0,0,0);
      f32x4 dhxy = __builtin_amdgcn_mfma_f32_16x16x32_bf16(afrag, bxy.v, zero4, 0,0,0);
      #pragma unroll
      for (int i = 0; i < 4; ++i) {
        const int c = C0 + g*4 + i;
        if (rok && c >= PAD && c < HW - PAD) {
          const float hx = dhx[i], hy = dhy[i];
          const float hxx = dhxx[i], hyy = dhyy[i], hxy = dhxy[i];
          const float sx = hxx - hx*hx, sy = hyy - hy*hy, sxy = hxy - hx*hy;
          const float num = (2.f*hx*hy + C1f) * (2.f*sxy + C2f);
          const float den = (hx*hx + hy*hy + C1f) * (sx + sy + C2f);
          accc += num * __builtin_amdgcn_rcpf(den);
        }
      }
      const float n1 = (float)(HW - 2*PAD);
      acc_total += accc * __builtin_amdgcn_rcpf(n1 * n1);
    }
  }

  // block reduction
  sm.red[t] = acc_total;
  __syncthreads();
  for (int off = 512; off > 0; off >>= 1) {
    if (t < off) sm.red[t] += sm.red[t+off];
    __syncthreads();
  }
  if (t == 0) partial[bid] = sm.red[0] * (1.f / (25.f * 128.f));
}

// ---------------- Kernel C: final deterministic reduction ----------------
__global__ __launch_bounds__(256)
void reduce_kernel(const float* __restrict__ partial, float* __restrict__ out)
{
  const int t = threadIdx.x;
  double s = 0.0;
  for (int i = t; i < NBLK; i += 256) s += (double)partial[i];
  __shared__ double red[256];
  red[t] = s;
  __syncthreads();
  for (int off = 128; off > 0; off >>= 1) {
    if (t < off) red[t] += red[t+off];
    __syncthreads();
  }
  if (t == 0) out[0] = (float)(0.5 - 0.5 * red[0]);
}

extern "C" void kernel_launch(void* const* d_in, const int* in_sizes, int n_in,
                              void* d_out, int out_size, void* d_ws, size_t ws_size,
                              hipStream_t stream) {
  const float* pred = (const float*)d_in[0];
  const float* targ = (const float*)d_in[1];
  float* out = (float*)d_out;
  float* ws = (float*)d_ws;
  float* stats   = ws;          // 512 floats
  float* partial = ws + 512;    // NBLK floats

  stats_kernel<<<256, 256, 0, stream>>>(pred, targ, stats);
  ssim_fused<<<NBLK, 1024, 0, stream>>>(pred, targ, stats, partial);
  reduce_kernel<<<1, 256, 0, stream>>>(partial, out);
}